// Round 5
// baseline (272.437 us; speedup 1.0000x reference)
//
#include <hip/hip_runtime.h>
#include <cstdint>
#include <cstddef>

#define D_MODEL  256
#define D_FLOW   128
#define D_FFN    1024
#define N_HEADS  8
#define N_LEVELS 3
#define N_POINTS 4
#define D_HEAD   32
#define LQ       16384
#define LENIN    21504
#define NB       2

typedef unsigned short ushort;
typedef __attribute__((ext_vector_type(8))) short bf16x8;   // 8 bf16 in 4 VGPRs
typedef __attribute__((ext_vector_type(4))) float f32x4;

__device__ __forceinline__ ushort f2b(float f) {            // fp32 -> bf16 RNE
    uint32_t u = __float_as_uint(f);
    uint32_t r = (u + 0x7fffu + ((u >> 16) & 1u)) >> 16;
    return (ushort)r;
}

// async 16B global->LDS copy; LDS dest = wave-uniform base + lane*16
__device__ __forceinline__ void gl_lds16(const void* g, void* l) {
    __builtin_amdgcn_global_load_lds(
        (const __attribute__((address_space(1))) unsigned int*)g,
        (__attribute__((address_space(3))) unsigned int*)l,
        16, 0, 0);
}

// ---------------------------------------------------------------------------
// bf16 MFMA GEMM: BM=BN=128, BK=64.  XCD-contiguous block swizzle (unchanged).
// ---------------------------------------------------------------------------
template<bool A_FP32, bool RELU, bool RESID, bool OUT_BF16>
__global__ __launch_bounds__(256)
void mfma_gemm(const void* __restrict__ Ain, const ushort* __restrict__ Bt,
               const float* __restrict__ bias, const float* __restrict__ resid,
               void* __restrict__ Cout, int N, int K)
{
    __shared__ ushort As[128 * 64];   // 16 KB
    __shared__ ushort Bs[128 * 64];   // 16 KB

    const int tid  = threadIdx.x;
    const int wave = tid >> 6;
    const int lane = tid & 63;
    const int quad = lane >> 4;
    const int l16  = lane & 15;
    const int wr   = (wave >> 1) * 64;
    const int wc   = (wave & 1) * 64;

    const int nx = gridDim.x;
    int lin = blockIdx.y * nx + blockIdx.x;
    const int total = nx * gridDim.y;
    if ((total & 7) == 0) lin = (lin & 7) * (total >> 3) + (lin >> 3);
    const int by = lin / nx;
    const int bx = lin - by * nx;
    const int bm = by * 128;
    const int bn = bx * 128;

    const int sr  = lane >> 3;
    const int sc  = lane & 7;
    const int gch = sc ^ sr;

    f32x4 acc[4][4] = {};
    const int swz = l16 & 7;

    for (int k0 = 0; k0 < K; k0 += 64) {
        __syncthreads();
        if (A_FP32) {
            const float* Af = (const float*)Ain;
#pragma unroll
            for (int i = 0; i < 4; ++i) {
                const int row = wave * 32 + i * 8 + sr;
                const float* p = Af + (size_t)(bm + row) * K + k0 + gch * 8;
                const float4 v0 = *(const float4*)(p);
                const float4 v1 = *(const float4*)(p + 4);
                bf16x8 pk;
                pk[0] = (short)f2b(v0.x); pk[1] = (short)f2b(v0.y);
                pk[2] = (short)f2b(v0.z); pk[3] = (short)f2b(v0.w);
                pk[4] = (short)f2b(v1.x); pk[5] = (short)f2b(v1.y);
                pk[6] = (short)f2b(v1.z); pk[7] = (short)f2b(v1.w);
                *(bf16x8*)&As[(size_t)row * 64 + sc * 8] = pk;
            }
        } else {
            const ushort* Ab = (const ushort*)Ain;
#pragma unroll
            for (int i = 0; i < 4; ++i) {
                const int row = wave * 32 + i * 8;
                gl_lds16(Ab + (size_t)(bm + row + sr) * K + k0 + gch * 8,
                         As + (size_t)row * 64);
            }
        }
#pragma unroll
        for (int i = 0; i < 4; ++i) {
            const int row = wave * 32 + i * 8;
            gl_lds16(Bt + (size_t)(bn + row + sr) * K + k0 + gch * 8,
                     Bs + (size_t)row * 64);
        }
        __syncthreads();

#pragma unroll
        for (int kk = 0; kk < 2; ++kk) {
            bf16x8 af[4], bfr[4];
#pragma unroll
            for (int mi = 0; mi < 4; ++mi) {
                const int p = (kk * 4 + quad) ^ swz;
                af[mi] = *(const bf16x8*)&As[(wr + mi * 16 + l16) * 64 + p * 8];
            }
#pragma unroll
            for (int ni = 0; ni < 4; ++ni) {
                const int p = (kk * 4 + quad) ^ swz;
                bfr[ni] = *(const bf16x8*)&Bs[(wc + ni * 16 + l16) * 64 + p * 8];
            }
#pragma unroll
            for (int mi = 0; mi < 4; ++mi)
#pragma unroll
                for (int ni = 0; ni < 4; ++ni)
                    acc[mi][ni] = __builtin_amdgcn_mfma_f32_16x16x32_bf16(
                        af[mi], bfr[ni], acc[mi][ni], 0, 0, 0);
        }
    }

#pragma unroll
    for (int mi = 0; mi < 4; ++mi) {
#pragma unroll
        for (int ni = 0; ni < 4; ++ni) {
            const int col = bn + wc + ni * 16 + l16;
            const float bb = bias[col];
#pragma unroll
            for (int r = 0; r < 4; ++r) {
                const int row = bm + wr + mi * 16 + quad * 4 + r;
                const size_t idx = (size_t)row * N + col;
                float c = acc[mi][ni][r] + bb;
                if (RELU)  c = fmaxf(c, 0.f);
                if (RESID) c += resid[idx];
                if (OUT_BF16) ((ushort*)Cout)[idx] = f2b(c);
                else          ((float*)Cout)[idx]  = c;
            }
        }
    }
}

// ---------------------------------------------------------------------------
// Fused out-projection GEMM + LayerNorm (unchanged).
// ---------------------------------------------------------------------------
__global__ __launch_bounds__(256)
void gemm_ln_k(const ushort* __restrict__ A, const ushort* __restrict__ Bt,
               const float* __restrict__ bias, const float* __restrict__ gamma,
               const float* __restrict__ beta,
               float* __restrict__ xout, ushort* __restrict__ lnout, int K)
{
    __shared__ ushort As[64 * 32];      // 4 KB
    __shared__ ushort Bs[256 * 32];     // 16 KB
    __shared__ float  sS[64][33];
    __shared__ float  sS2[64][33];
    __shared__ float  sMu[64], sRi[64];

    const int tid  = threadIdx.x;
    const int wave = tid >> 6;
    const int lane = tid & 63;
    const int quad = lane >> 4;
    const int l16  = lane & 15;
    const int wr   = (wave >> 1) * 32;
    const int wc   = (wave & 1) * 128;
    const int bm   = blockIdx.x * 64;

    const int sr  = lane >> 2;          // 0..15
    const int sc  = lane & 3;
    const int gch = sc ^ (sr & 3);

    f32x4 acc[2][8] = {};
    const int swz = l16 & 3;

    for (int k0 = 0; k0 < K; k0 += 32) {
        __syncthreads();
        gl_lds16(A + (size_t)(bm + wave * 16 + sr) * K + k0 + gch * 8,
                 As + wave * 16 * 32);
#pragma unroll
        for (int i = 0; i < 4; ++i) {
            const int row = wave * 64 + i * 16;
            gl_lds16(Bt + (size_t)(row + sr) * K + k0 + gch * 8,
                     Bs + (size_t)row * 32);
        }
        __syncthreads();

        bf16x8 af[2], bfr[8];
#pragma unroll
        for (int mi = 0; mi < 2; ++mi)
            af[mi] = *(const bf16x8*)&As[(wr + mi * 16 + l16) * 32 + ((quad ^ swz) << 3)];
#pragma unroll
        for (int ni = 0; ni < 8; ++ni)
            bfr[ni] = *(const bf16x8*)&Bs[(wc + ni * 16 + l16) * 32 + ((quad ^ swz) << 3)];
#pragma unroll
        for (int mi = 0; mi < 2; ++mi)
#pragma unroll
            for (int ni = 0; ni < 8; ++ni)
                acc[mi][ni] = __builtin_amdgcn_mfma_f32_16x16x32_bf16(
                    af[mi], bfr[ni], acc[mi][ni], 0, 0, 0);
    }

    float bias8[8], g8[8], b8[8];
#pragma unroll
    for (int ni = 0; ni < 8; ++ni) {
        const int col = wc + ni * 16 + l16;
        bias8[ni] = bias[col];
        g8[ni]    = gamma[col];
        b8[ni]    = beta[col];
    }

#pragma unroll
    for (int mi = 0; mi < 2; ++mi)
#pragma unroll
        for (int r = 0; r < 4; ++r) {
            float s = 0.f, s2 = 0.f;
#pragma unroll
            for (int ni = 0; ni < 8; ++ni) {
                const float c = acc[mi][ni][r] + bias8[ni];
                s += c; s2 += c * c;
            }
            const int row = wr + mi * 16 + quad * 4 + r;
            sS[row][(wave & 1) * 16 + l16]  = s;
            sS2[row][(wave & 1) * 16 + l16] = s2;
        }
    __syncthreads();

    if (tid < 64) {
        float s = 0.f, s2 = 0.f;
#pragma unroll
        for (int j = 0; j < 32; ++j) { s += sS[tid][j]; s2 += sS2[tid][j]; }
        const float mu  = s * (1.f / 256.f);
        const float var = s2 * (1.f / 256.f) - mu * mu;
        sMu[tid] = mu;
        sRi[tid] = rsqrtf(var + 1e-5f);
    }
    __syncthreads();

#pragma unroll
    for (int mi = 0; mi < 2; ++mi)
#pragma unroll
        for (int r = 0; r < 4; ++r) {
            const int lrow = wr + mi * 16 + quad * 4 + r;
            const int grow = bm + lrow;
            const float mu = sMu[lrow], ri = sRi[lrow];
#pragma unroll
            for (int ni = 0; ni < 8; ++ni) {
                const int col = wc + ni * 16 + l16;
                const float c = acc[mi][ni][r] + bias8[ni];
                xout[(size_t)grow * 256 + col]  = c;
                lnout[(size_t)grow * 256 + col] = f2b((c - mu) * ri * g8[ni] + b8[ni]);
            }
        }
}

// ---------------------------------------------------------------------------
// Fused FFN v5: v4 structure (all-waves symmetric, operand-swapped MFMA,
// identical fragment layouts / swizzles / accumulation order) with BM=64 so
// grid=512 -> 2 blocks/CU (r4 lesson: 1 block/CU leaves barrier drains
// uncovered; occupancy was the binding constraint, not LDS port).
// out = x + relu(ln @ w1 + b1) @ w2 + b2; H never leaves the CU.
// BM=64, 512 thr (8 waves), 16 chunks of 64 FFN cols.
//   GEMM1: wave tile 16 ln-rows x 32 w1-cols (4m x 2n); ln frags in regs.
//   GEMM2: wave tile 32 rows x 64 cols (2m x 4n).
// LDS 72 KB dynamic (2 blocks/CU = 144 KB <= 160 KB):
//   w1s [64][256] 32K | w2s [256][64] 32K | hS [64][64] 8K; lnS 32K
//   prologue alias over w1s.
// Schedule/iter: [stage w2(c) | GEMM1(c) | write H(c)] B1
//                [stage w1(c+1) | GEMM2(c)] B2
// ---------------------------------------------------------------------------
__global__ __launch_bounds__(512, 4)
void ffn_fused_k(const ushort* __restrict__ ln, const ushort* __restrict__ w1T,
                 const ushort* __restrict__ w2C, const float* __restrict__ b1v,
                 const float* __restrict__ b2v, float* __restrict__ out)
{
    extern __shared__ ushort smem[];               // 73728 B dynamic
    ushort* const w1s = smem;                      // [64 n][256 k]  32 KB
    ushort* const w2s = smem + 16384;              // [256 n][64 k]  32 KB
    ushort* const hS  = smem + 32768;              // [64 m][64 n]    8 KB
    ushort* const lnS = smem;                      // [64][256] 32 KB prologue

    const int tid  = threadIdx.x;
    const int wave = tid >> 6;
    const int lane = tid & 63;
    const int quad = lane >> 4;
    const int l16  = lane & 15;
    const int bm   = blockIdx.x * 64;

    const int R0g1 = (wave >> 1) * 16;   // GEMM1: ln-row base (4 bands of 16)
    const int C0g1 = (wave & 1) * 32;    // GEMM1: w1-col base (within chunk)
    const int M0   = (wave & 1) * 32;    // GEMM2: out-row base
    const int N0   = (wave >> 1) * 64;   // GEMM2: out-col base

    // ---- prologue: stage ln tile (32 KB over w1s), load A-frags ------------
#pragma unroll
    for (int i = 0; i < 4; ++i) {
        const int r0 = (wave * 4 + i) * 2;
        const int r  = r0 + (lane >> 5);
        gl_lds16(ln + (size_t)(bm + r) * 256 + (((lane & 31) ^ (r & 7)) << 3),
                 lnS + r0 * 256);
    }
    __syncthreads();

    bf16x8 afA[8];                       // ln rows R0g1..+15 x K=256
#pragma unroll
    for (int kk = 0; kk < 8; ++kk) {
        const int row = R0g1 + l16;
        afA[kk] = *(const bf16x8*)
            &lnS[row * 256 + (((kk * 4 + quad) ^ (row & 7)) << 3)];
    }
    __syncthreads();                     // lnS dead

    // stage w1 chunk 0
#pragma unroll
    for (int i = 0; i < 4; ++i) {
        const int r0 = (wave * 4 + i) * 2;
        const int r  = r0 + (lane >> 5);
        gl_lds16(w1T + (size_t)r * 256 + (((lane & 31) ^ (r & 7)) << 3),
                 w1s + r0 * 256);
    }
    __syncthreads();

    f32x4 acc2[2][4] = {};               // out[m=M0+mt*16+l16][n=N0+nt*16+q*4+r]

#pragma unroll 1
    for (int c = 0; c < 16; ++c) {
        // ===== phase 1: stage w2(c) | GEMM1(c) | write H(c) =====
        {
            const ushort* src = w2C + (size_t)c * 16384;
#pragma unroll
            for (int i = 0; i < 4; ++i) {
                const int r0 = (wave * 4 + i) * 8;       // 8 rows of 128 B
                const int r  = r0 + (lane >> 3);
                gl_lds16(src + (size_t)r * 64 + (((lane & 7) ^ (r & 7)) << 3),
                         w2s + r0 * 64);
            }
        }

        f32x4 acc1[2] = {};
#pragma unroll
        for (int kk = 0; kk < 8; ++kk) {
            bf16x8 wf[2];
#pragma unroll
            for (int nt = 0; nt < 2; ++nt) {
                const int n = C0g1 + nt * 16 + l16;
                wf[nt] = *(const bf16x8*)
                    &w1s[n * 256 + (((kk * 4 + quad) ^ (n & 7)) << 3)];
            }
#pragma unroll
            for (int nt = 0; nt < 2; ++nt)
                acc1[nt] = __builtin_amdgcn_mfma_f32_16x16x32_bf16(
                    wf[nt], afA[kk], acc1[nt], 0, 0, 0);
        }

        // H(c): lane holds H[m=R0g1+l16][n=C0g1+nt*16+quad*4+r]
        {
            float4 bb[2];
#pragma unroll
            for (int nt = 0; nt < 2; ++nt)
                bb[nt] = *(const float4*)&b1v[c * 64 + C0g1 + nt * 16 + quad * 4];
            const int m = R0g1 + l16;
#pragma unroll
            for (int nt = 0; nt < 2; ++nt) {
                const int oct = (C0g1 >> 2) + nt * 4 + quad;
                ushort4 pk;
                pk.x = f2b(fmaxf(acc1[nt][0] + bb[nt].x, 0.f));
                pk.y = f2b(fmaxf(acc1[nt][1] + bb[nt].y, 0.f));
                pk.z = f2b(fmaxf(acc1[nt][2] + bb[nt].z, 0.f));
                pk.w = f2b(fmaxf(acc1[nt][3] + bb[nt].w, 0.f));
                *(ushort4*)&hS[m * 64 + ((oct ^ ((m & 7) << 1)) << 2)] = pk;
            }
        }
        __syncthreads();                 // B1: w2(c) drained, H(c) visible

        // ===== phase 2: stage w1(c+1) | GEMM2(c) =====
        if (c < 15) {
#pragma unroll
            for (int i = 0; i < 4; ++i) {
                const int r0 = (wave * 4 + i) * 2;
                const int r  = r0 + (lane >> 5);
                gl_lds16(w1T + (size_t)((c + 1) * 64 + r) * 256
                             + (((lane & 31) ^ (r & 7)) << 3),
                         w1s + r0 * 256);
            }
        }

#pragma unroll
        for (int kk = 0; kk < 2; ++kk) {
            const int g = kk * 4 + quad;
            bf16x8 hf[2], wf2[4];
#pragma unroll
            for (int mt = 0; mt < 2; ++mt) {
                const int m = M0 + mt * 16 + l16;
                hf[mt] = *(const bf16x8*)&hS[m * 64 + ((g ^ (m & 7)) << 3)];
            }
#pragma unroll
            for (int nt = 0; nt < 4; ++nt) {
                const int n = N0 + nt * 16 + l16;
                wf2[nt] = *(const bf16x8*)&w2s[n * 64 + ((g ^ (n & 7)) << 3)];
            }
#pragma unroll
            for (int mt = 0; mt < 2; ++mt)
#pragma unroll
                for (int nt = 0; nt < 4; ++nt)
                    acc2[mt][nt] = __builtin_amdgcn_mfma_f32_16x16x32_bf16(
                        wf2[nt], hf[mt], acc2[mt][nt], 0, 0, 0);
        }
        __syncthreads();                 // B2: w1(c+1) drained, H reads done
    }

    // ---- epilogue: out = x + acc2 + b2 (float4 RMW, out holds x) ----------
#pragma unroll
    for (int mt = 0; mt < 2; ++mt) {
        const int row = bm + M0 + mt * 16 + l16;
#pragma unroll
        for (int nt = 0; nt < 4; ++nt) {
            const int col = N0 + nt * 16 + quad * 4;
            float4* p = (float4*)(out + (size_t)row * 256 + col);
            const float4 b4 = *(const float4*)&b2v[col];
            float4 v = *p;
            v.x = v.x + acc2[mt][nt][0] + b4.x;
            v.y = v.y + acc2[mt][nt][1] + b4.y;
            v.z = v.z + acc2[mt][nt][2] + b4.z;
            v.w = v.w + acc2[mt][nt][3] + b4.w;
            *p = v;
        }
    }
}

// ---------------------------------------------------------------------------
// Fused softmax + deformable bilinear sampling (unchanged).
// ---------------------------------------------------------------------------
__device__ __forceinline__ void acc8(float* a, uint4 g, float w) {
    a[0] = fmaf(w, __uint_as_float(g.x << 16), a[0]);
    a[1] = fmaf(w, __uint_as_float(g.x), a[1]);
    a[2] = fmaf(w, __uint_as_float(g.y << 16), a[2]);
    a[3] = fmaf(w, __uint_as_float(g.y), a[3]);
    a[4] = fmaf(w, __uint_as_float(g.z << 16), a[4]);
    a[5] = fmaf(w, __uint_as_float(g.z), a[5]);
    a[6] = fmaf(w, __uint_as_float(g.w << 16), a[6]);
    a[7] = fmaf(w, __uint_as_float(g.w), a[7]);
}

__global__ __launch_bounds__(256)
void sample_k(const ushort* __restrict__ value, const ushort* __restrict__ projc,
              ushort* __restrict__ acc)
{
    __shared__ float sOff[8][192];
    __shared__ float sAttn[8][96];

    const int tid = threadIdx.x;
    const int bid = blockIdx.x;                       // 0..4095
    const int bq0 = (((bid & 7) << 9) | (bid >> 3)) << 3;   // XCD stripe swizzle

    for (int i = tid; i < 8 * 288; i += 256) {
        const int qw = i / 288, j = i - qw * 288;
        const float v = __uint_as_float((uint32_t)projc[(size_t)(bq0 + qw) * 384 + j] << 16);
        if (j < 192) sOff[qw][j] = v;
        else         sAttn[qw][j - 192] = v;
    }
    __syncthreads();

    if (tid < 64) {
        const int qw = tid >> 3, h = tid & 7;
        float* row = &sAttn[qw][h * 12];
        float m = row[0];
#pragma unroll
        for (int j = 1; j < 12; ++j) m = fmaxf(m, row[j]);
        float s = 0.f;
#pragma unroll
        for (int j = 0; j < 12; ++j) { const float e = __expf(row[j] - m); row[j] = e; s += e; }
        const float inv = 1.f / s;
#pragma unroll
        for (int j = 0; j < 12; ++j) row[j] *= inv;
    }
    __syncthreads();

    const int wave = tid >> 6, lane = tid & 63;
    const int qh = lane >> 5;
    const int h  = (lane >> 2) & 7;
    const int cg = lane & 3;
    const int qw = wave * 2 + qh;
    const int bq = bq0 + qw;
    const int n  = bq >> 14;
    const int q  = bq & 16383;

    const float qx = (float)(q & 127) + 0.5f;
    const float qy = (float)(q >> 7) + 0.5f;

    const int LSIc[3] = {0, 16384, 20480};

    float a[8] = {0.f, 0.f, 0.f, 0.f, 0.f, 0.f, 0.f, 0.f};
    const ushort* vbase = value + (size_t)n * LENIN * D_MODEL + h * D_HEAD + cg * 8;

#pragma unroll
    for (int l = 0; l < N_LEVELS; ++l) {
        const int   W     = 128 >> l;
        const int   SH    = 7 - l;
        const float scale = 1.f / (float)(1 << l);
        const float cx    = qx * scale - 0.5f;
        const float cy    = qy * scale - 0.5f;
        const ushort* vlev = vbase + ((size_t)LSIc[l] << 8);
#pragma unroll
        for (int p = 0; p < N_POINTS; ++p) {
            const int ob = (h * N_LEVELS + l) * (N_POINTS * 2) + p * 2;
            const float aw = sAttn[qw][h * 12 + l * 4 + p];
            const float x = cx + sOff[qw][ob];
            const float y = cy + sOff[qw][ob + 1];
            const float x0f = floorf(x), y0f = floorf(y);
            const int x0 = (int)x0f, y0 = (int)y0f;
            const float dx = x - x0f, dy = y - y0f;
            float wx1 = dx * aw, wx0 = aw - wx1;
            float wy1 = dy,      wy0 = 1.f - dy;
            if ((unsigned)x0       > (unsigned)(W - 1)) wx0 = 0.f;
            if ((unsigned)(x0 + 1) > (unsigned)(W - 1)) wx1 = 0.f;
            if ((unsigned)y0       > (unsigned)(W - 1)) wy0 = 0.f;
            if ((unsigned)(y0 + 1) > (unsigned)(W - 1)) wy1 = 0.f;
            const int xi0 = min(max(x0, 0), W - 1);
            const int xi1 = min(max(x0 + 1, 0), W - 1);
            const int yi0 = min(max(y0, 0), W - 1);
            const int yi1 = min(max(y0 + 1, 0), W - 1);
            const uint4 g00 = *(const uint4*)(vlev + ((size_t)((yi0 << SH) + xi0) << 8));
            const uint4 g01 = *(const uint4*)(vlev + ((size_t)((yi0 << SH) + xi1) << 8));
            const uint4 g10 = *(const uint4*)(vlev + ((size_t)((yi1 << SH) + xi0) << 8));
            const uint4 g11 = *(const uint4*)(vlev + ((size_t)((yi1 << SH) + xi1) << 8));
            acc8(a, g00, wx0 * wy0);
            acc8(a, g01, wx1 * wy0);
            acc8(a, g10, wx0 * wy1);
            acc8(a, g11, wx1 * wy1);
        }
    }

    const uint32_t o0 = (uint32_t)f2b(a[0]) | ((uint32_t)f2b(a[1]) << 16);
    const uint32_t o1 = (uint32_t)f2b(a[2]) | ((uint32_t)f2b(a[3]) << 16);
    const uint32_t o2 = (uint32_t)f2b(a[4]) | ((uint32_t)f2b(a[5]) << 16);
    const uint32_t o3 = (uint32_t)f2b(a[6]) | ((uint32_t)f2b(a[7]) << 16);
    const uint4 ov = {o0, o1, o2, o3};
    *(uint4*)(acc + (size_t)bq * D_MODEL + h * D_HEAD + cg * 8) = ov;
}

// ---------------------------------------------------------------------------
// All weight prep in one launch.  w2 stored CHUNK-MAJOR for 64-col chunks:
//   w2C[c][n][kk] = w2[c*64+kk][n]   (c=0..15, n=0..255, kk=0..63)
// ---------------------------------------------------------------------------
__global__ __launch_bounds__(256)
void prep_all_k(const float* __restrict__ w_value, const float* __restrict__ w_out,
                const float* __restrict__ w1, const float* __restrict__ w2,
                const float* __restrict__ w_off, const float* __restrict__ b_off,
                const float* __restrict__ w_attn, const float* __restrict__ b_attn,
                ushort* __restrict__ wvT, ushort* __restrict__ woT,
                ushort* __restrict__ w1T, ushort* __restrict__ w2C,
                ushort* __restrict__ wcT, float* __restrict__ biasc)
{
    int i = blockIdx.x * 256 + threadIdx.x;
    if (i < 65536) {                                  // w_value [256][256] -> [n][k]
        const int k = i >> 8, n = i & 255;
        wvT[(size_t)n * 256 + k] = f2b(w_value[i]);
        return;
    }
    i -= 65536;
    if (i < 65536) {                                  // w_out [256][256]
        const int k = i >> 8, n = i & 255;
        woT[(size_t)n * 256 + k] = f2b(w_out[i]);
        return;
    }
    i -= 65536;
    if (i < 262144) {                                 // w1 [256][1024] -> [1024][256]
        const int k = i >> 10, n = i & 1023;
        w1T[(size_t)n * 256 + k] = f2b(w1[i]);
        return;
    }
    i -= 262144;
    if (i < 262144) {                                 // w2 [1024][256] -> chunk-major 64
        const int k = i >> 8, n = i & 255;
        w2C[(size_t)(k >> 6) * 16384 + n * 64 + (k & 63)] = f2b(w2[i]);
        return;
    }
    i -= 262144;
    if (i < 49152) {                                  // [w_off|w_attn|0] -> [384][128]
        const int nn = i >> 7, k = i & 127;
        float v = 0.f;
        if (nn < 192)      v = w_off[(size_t)k * 192 + nn];
        else if (nn < 288) v = w_attn[(size_t)k * 96 + (nn - 192)];
        wcT[i] = f2b(v);
        return;
    }
    i -= 49152;
    if (i < 384) {
        float b = 0.f;
        if (i < 192)      b = b_off[i];
        else if (i < 288) b = b_attn[i - 192];
        biasc[i] = b;
    }
}

// ---------------------------------------------------------------------------
extern "C" void kernel_launch(void* const* d_in, const int* in_sizes, int n_in,
                              void* d_out, int out_size, void* d_ws, size_t ws_size,
                              hipStream_t stream)
{
    const float* src     = (const float*)d_in[0];
    const float* flow    = (const float*)d_in[1];
    const float* w_value = (const float*)d_in[4];
    const float* b_value = (const float*)d_in[5];
    const float* w_off   = (const float*)d_in[6];
    const float* b_off   = (const float*)d_in[7];
    const float* w_attn  = (const float*)d_in[8];
    const float* b_attn  = (const float*)d_in[9];
    const float* w_out   = (const float*)d_in[10];
    const float* b_out   = (const float*)d_in[11];
    const float* gamma   = (const float*)d_in[12];
    const float* beta    = (const float*)d_in[13];
    const float* w1      = (const float*)d_in[14];
    const float* b1      = (const float*)d_in[15];
    const float* w2      = (const float*)d_in[16];
    const float* b2      = (const float*)d_in[17];
    float* out = (float*)d_out;
    char*  wsb = (char*)d_ws;

    // Workspace (bytes), lifetime-aliased:
    //   [0, 22MB)               value_bf
    //   [22MB, 39MB)            acc_bf
    //   [67108864, 92274688)    projc_bf (dead after sampler) -> ln_bf
    //   [92274688, ...)         bf16 weights + proj bias
    ushort* value_bf = (ushort*)(wsb);
    ushort* acc_bf   = (ushort*)(wsb + 22020096);
    ushort* projc_bf = (ushort*)(wsb + 67108864);
    ushort* ln_bf    = (ushort*)(wsb + 67108864);
    ushort* wvT      = (ushort*)(wsb + 92274688);
    ushort* woT      = (ushort*)(wsb + 92405760);
    ushort* w1T      = (ushort*)(wsb + 92536832);
    ushort* w2C      = (ushort*)(wsb + 93061120);
    ushort* wcT      = (ushort*)(wsb + 93585408);
    float*  biasc    = (float*) (wsb + 93683712);

    const int Mq = NB * LQ;     // 32768
    const int Mv = NB * LENIN;  // 43008

    // allow 72 KB dynamic LDS for the fused FFN (idempotent)
    static bool ffn_attr_done = false;
    if (!ffn_attr_done) {
        hipFuncSetAttribute((const void*)ffn_fused_k,
                            hipFuncAttributeMaxDynamicSharedMemorySize, 73728);
        ffn_attr_done = true;
    }

    // 0. all weight prep, one launch
    prep_all_k<<<2754, 256, 0, stream>>>(w_value, w_out, w1, w2,
                                         w_off, b_off, w_attn, b_attn,
                                         wvT, woT, w1T, w2C, wcT, biasc);

    // 1. value = src @ w_value + b_value  [43008 x 256] (fp32 A staged) bf16 out
    mfma_gemm<true, false, false, true><<<dim3(2, Mv / 128), 256, 0, stream>>>(
        src, wvT, b_value, nullptr, value_bf, 256, 256);

    // 2. proj = flow @ [w_off|w_attn|0] + bias  [32768 x 384] (fp32 A) bf16 out
    mfma_gemm<true, false, false, true><<<dim3(3, Mq / 128), 256, 0, stream>>>(
        flow, wcT, biasc, nullptr, projc_bf, 384, 128);

    // 3. deformable sampling (fused softmax)  [32768 x 256] bf16 out
    sample_k<<<Mq / 8, 256, 0, stream>>>(value_bf, projc_bf, acc_bf);

    // 4. x = acc @ w_out + b_out -> d_out fp32; ln = LN(x) -> bf16 (fused)
    gemm_ln_k<<<Mq / 64, 256, 0, stream>>>(
        acc_bf, woT, b_out, gamma, beta, out, ln_bf, 256);

    // 5+6 fused: out = x + relu(ln @ w1 + b1) @ w2 + b2  (BM=64, 2 blocks/CU)
    ffn_fused_k<<<Mq / 64, 512, 73728, stream>>>(ln_bf, w1T, w2C, b1, b2, out);
}

// Round 6
// 269.775 us; speedup vs baseline: 1.0099x; 1.0099x over previous
//
#include <hip/hip_runtime.h>
#include <cstdint>
#include <cstddef>

#define D_MODEL  256
#define D_FLOW   128
#define D_FFN    1024
#define N_HEADS  8
#define N_LEVELS 3
#define N_POINTS 4
#define D_HEAD   32
#define LQ       16384
#define LENIN    21504
#define NB       2

typedef unsigned short ushort;
typedef __attribute__((ext_vector_type(8))) short bf16x8;   // 8 bf16 in 4 VGPRs
typedef __attribute__((ext_vector_type(4))) float f32x4;

__device__ __forceinline__ ushort f2b(float f) {            // fp32 -> bf16 RNE
    uint32_t u = __float_as_uint(f);
    uint32_t r = (u + 0x7fffu + ((u >> 16) & 1u)) >> 16;
    return (ushort)r;
}

// async 16B global->LDS copy; LDS dest = wave-uniform base + lane*16
__device__ __forceinline__ void gl_lds16(const void* g, void* l) {
    __builtin_amdgcn_global_load_lds(
        (const __attribute__((address_space(1))) unsigned int*)g,
        (__attribute__((address_space(3))) unsigned int*)l,
        16, 0, 0);
}

// ---------------------------------------------------------------------------
// bf16 MFMA GEMM: BM=BN=128, BK=64.  XCD-contiguous block swizzle (unchanged).
// ---------------------------------------------------------------------------
template<bool A_FP32, bool RELU, bool RESID, bool OUT_BF16>
__global__ __launch_bounds__(256)
void mfma_gemm(const void* __restrict__ Ain, const ushort* __restrict__ Bt,
               const float* __restrict__ bias, const float* __restrict__ resid,
               void* __restrict__ Cout, int N, int K)
{
    __shared__ ushort As[128 * 64];   // 16 KB
    __shared__ ushort Bs[128 * 64];   // 16 KB

    const int tid  = threadIdx.x;
    const int wave = tid >> 6;
    const int lane = tid & 63;
    const int quad = lane >> 4;
    const int l16  = lane & 15;
    const int wr   = (wave >> 1) * 64;
    const int wc   = (wave & 1) * 64;

    const int nx = gridDim.x;
    int lin = blockIdx.y * nx + blockIdx.x;
    const int total = nx * gridDim.y;
    if ((total & 7) == 0) lin = (lin & 7) * (total >> 3) + (lin >> 3);
    const int by = lin / nx;
    const int bx = lin - by * nx;
    const int bm = by * 128;
    const int bn = bx * 128;

    const int sr  = lane >> 3;
    const int sc  = lane & 7;
    const int gch = sc ^ sr;

    f32x4 acc[4][4] = {};
    const int swz = l16 & 7;

    for (int k0 = 0; k0 < K; k0 += 64) {
        __syncthreads();
        if (A_FP32) {
            const float* Af = (const float*)Ain;
#pragma unroll
            for (int i = 0; i < 4; ++i) {
                const int row = wave * 32 + i * 8 + sr;
                const float* p = Af + (size_t)(bm + row) * K + k0 + gch * 8;
                const float4 v0 = *(const float4*)(p);
                const float4 v1 = *(const float4*)(p + 4);
                bf16x8 pk;
                pk[0] = (short)f2b(v0.x); pk[1] = (short)f2b(v0.y);
                pk[2] = (short)f2b(v0.z); pk[3] = (short)f2b(v0.w);
                pk[4] = (short)f2b(v1.x); pk[5] = (short)f2b(v1.y);
                pk[6] = (short)f2b(v1.z); pk[7] = (short)f2b(v1.w);
                *(bf16x8*)&As[(size_t)row * 64 + sc * 8] = pk;
            }
        } else {
            const ushort* Ab = (const ushort*)Ain;
#pragma unroll
            for (int i = 0; i < 4; ++i) {
                const int row = wave * 32 + i * 8;
                gl_lds16(Ab + (size_t)(bm + row + sr) * K + k0 + gch * 8,
                         As + (size_t)row * 64);
            }
        }
#pragma unroll
        for (int i = 0; i < 4; ++i) {
            const int row = wave * 32 + i * 8;
            gl_lds16(Bt + (size_t)(bn + row + sr) * K + k0 + gch * 8,
                     Bs + (size_t)row * 64);
        }
        __syncthreads();

#pragma unroll
        for (int kk = 0; kk < 2; ++kk) {
            bf16x8 af[4], bfr[4];
#pragma unroll
            for (int mi = 0; mi < 4; ++mi) {
                const int p = (kk * 4 + quad) ^ swz;
                af[mi] = *(const bf16x8*)&As[(wr + mi * 16 + l16) * 64 + p * 8];
            }
#pragma unroll
            for (int ni = 0; ni < 4; ++ni) {
                const int p = (kk * 4 + quad) ^ swz;
                bfr[ni] = *(const bf16x8*)&Bs[(wc + ni * 16 + l16) * 64 + p * 8];
            }
#pragma unroll
            for (int mi = 0; mi < 4; ++mi)
#pragma unroll
                for (int ni = 0; ni < 4; ++ni)
                    acc[mi][ni] = __builtin_amdgcn_mfma_f32_16x16x32_bf16(
                        af[mi], bfr[ni], acc[mi][ni], 0, 0, 0);
        }
    }

#pragma unroll
    for (int mi = 0; mi < 4; ++mi) {
#pragma unroll
        for (int ni = 0; ni < 4; ++ni) {
            const int col = bn + wc + ni * 16 + l16;
            const float bb = bias[col];
#pragma unroll
            for (int r = 0; r < 4; ++r) {
                const int row = bm + wr + mi * 16 + quad * 4 + r;
                const size_t idx = (size_t)row * N + col;
                float c = acc[mi][ni][r] + bb;
                if (RELU)  c = fmaxf(c, 0.f);
                if (RESID) c += resid[idx];
                if (OUT_BF16) ((ushort*)Cout)[idx] = f2b(c);
                else          ((float*)Cout)[idx]  = c;
            }
        }
    }
}

// ---------------------------------------------------------------------------
// Fused out-projection GEMM + LayerNorm (unchanged).
// ---------------------------------------------------------------------------
__global__ __launch_bounds__(256)
void gemm_ln_k(const ushort* __restrict__ A, const ushort* __restrict__ Bt,
               const float* __restrict__ bias, const float* __restrict__ gamma,
               const float* __restrict__ beta,
               float* __restrict__ xout, ushort* __restrict__ lnout, int K)
{
    __shared__ ushort As[64 * 32];      // 4 KB
    __shared__ ushort Bs[256 * 32];     // 16 KB
    __shared__ float  sS[64][33];
    __shared__ float  sS2[64][33];
    __shared__ float  sMu[64], sRi[64];

    const int tid  = threadIdx.x;
    const int wave = tid >> 6;
    const int lane = tid & 63;
    const int quad = lane >> 4;
    const int l16  = lane & 15;
    const int wr   = (wave >> 1) * 32;
    const int wc   = (wave & 1) * 128;
    const int bm   = blockIdx.x * 64;

    const int sr  = lane >> 2;          // 0..15
    const int sc  = lane & 3;
    const int gch = sc ^ (sr & 3);

    f32x4 acc[2][8] = {};
    const int swz = l16 & 3;

    for (int k0 = 0; k0 < K; k0 += 32) {
        __syncthreads();
        gl_lds16(A + (size_t)(bm + wave * 16 + sr) * K + k0 + gch * 8,
                 As + wave * 16 * 32);
#pragma unroll
        for (int i = 0; i < 4; ++i) {
            const int row = wave * 64 + i * 16;
            gl_lds16(Bt + (size_t)(row + sr) * K + k0 + gch * 8,
                     Bs + (size_t)row * 32);
        }
        __syncthreads();

        bf16x8 af[2], bfr[8];
#pragma unroll
        for (int mi = 0; mi < 2; ++mi)
            af[mi] = *(const bf16x8*)&As[(wr + mi * 16 + l16) * 32 + ((quad ^ swz) << 3)];
#pragma unroll
        for (int ni = 0; ni < 8; ++ni)
            bfr[ni] = *(const bf16x8*)&Bs[(wc + ni * 16 + l16) * 32 + ((quad ^ swz) << 3)];
#pragma unroll
        for (int mi = 0; mi < 2; ++mi)
#pragma unroll
            for (int ni = 0; ni < 8; ++ni)
                acc[mi][ni] = __builtin_amdgcn_mfma_f32_16x16x32_bf16(
                    af[mi], bfr[ni], acc[mi][ni], 0, 0, 0);
    }

    float bias8[8], g8[8], b8[8];
#pragma unroll
    for (int ni = 0; ni < 8; ++ni) {
        const int col = wc + ni * 16 + l16;
        bias8[ni] = bias[col];
        g8[ni]    = gamma[col];
        b8[ni]    = beta[col];
    }

#pragma unroll
    for (int mi = 0; mi < 2; ++mi)
#pragma unroll
        for (int r = 0; r < 4; ++r) {
            float s = 0.f, s2 = 0.f;
#pragma unroll
            for (int ni = 0; ni < 8; ++ni) {
                const float c = acc[mi][ni][r] + bias8[ni];
                s += c; s2 += c * c;
            }
            const int row = wr + mi * 16 + quad * 4 + r;
            sS[row][(wave & 1) * 16 + l16]  = s;
            sS2[row][(wave & 1) * 16 + l16] = s2;
        }
    __syncthreads();

    if (tid < 64) {
        float s = 0.f, s2 = 0.f;
#pragma unroll
        for (int j = 0; j < 32; ++j) { s += sS[tid][j]; s2 += sS2[tid][j]; }
        const float mu  = s * (1.f / 256.f);
        const float var = s2 * (1.f / 256.f) - mu * mu;
        sMu[tid] = mu;
        sRi[tid] = rsqrtf(var + 1e-5f);
    }
    __syncthreads();

#pragma unroll
    for (int mi = 0; mi < 2; ++mi)
#pragma unroll
        for (int r = 0; r < 4; ++r) {
            const int lrow = wr + mi * 16 + quad * 4 + r;
            const int grow = bm + lrow;
            const float mu = sMu[lrow], ri = sRi[lrow];
#pragma unroll
            for (int ni = 0; ni < 8; ++ni) {
                const int col = wc + ni * 16 + l16;
                const float c = acc[mi][ni][r] + bias8[ni];
                xout[(size_t)grow * 256 + col]  = c;
                lnout[(size_t)grow * 256 + col] = f2b((c - mu) * ri * g8[ni] + b8[ni]);
            }
        }
}

// ---------------------------------------------------------------------------
// Fused FFN v6: v4 geometry (BM=128, chunk=64, grid 256, 8 waves) with
// SINGLE barrier per chunk + w2 in REGISTERS (no w2s LDS buffer).
// out = x + relu(ln @ w1 + b1) @ w2 + b2; H never leaves the CU.
// Per iter c: [issue stage w1(c+1)->w1[(c+1)&1] | load w2-frags(c-1) global->
//   regs (coalesced via frag-contiguous w2R layout) | GEMM1(c) from w1[c&1] |
//   H(c)->h[c&1] | GEMM2(c-1) from h[(c-1)&1]+reg-w2] barrier.
// Races: every concurrent pair hits opposite buffers (w1 dbuf, h dbuf);
// barrier at iter end drains the stage + publishes h(c).
// afA loaded directly from global (no lnS prologue stage).  All fragment
// values bit-identical to v4 (swizzle algebra cancels) -> same output.
// LDS 96 KB dynamic: w1[2] 2x32K | h[2] 2x16K.  ~212 VGPR (2 waves/SIMD).
// 16 barriers total vs v4's 33; LDS traffic/iter 256->192 KB.
// ---------------------------------------------------------------------------
__global__ __launch_bounds__(512, 2)
void ffn_fused_k(const ushort* __restrict__ ln, const ushort* __restrict__ w1T,
                 const ushort* __restrict__ w2R, const float* __restrict__ b1v,
                 const float* __restrict__ b2v, float* __restrict__ out)
{
    extern __shared__ ushort smem[];               // 98304 B dynamic
    ushort* const w1s0 = smem;                     // [64 n][256 k] 32 KB
    ushort* const w1s1 = smem + 16384;             // 32 KB
    ushort* const hs0  = smem + 32768;             // [128 m][64 n] 16 KB
    ushort* const hs1  = smem + 40960;             // 16 KB

    const int tid  = threadIdx.x;
    const int wave = tid >> 6;
    const int lane = tid & 63;
    const int quad = lane >> 4;
    const int l16  = lane & 15;
    const int bm   = blockIdx.x * 128;

    const int R0g1 = (wave >> 1) * 32;   // GEMM1: ln-row base
    const int C0g1 = (wave & 1) * 32;    // GEMM1: w1-col base (within chunk)
    const int M0   = (wave & 1) * 64;    // GEMM2: out-row base
    const int N0   = (wave >> 1) * 64;   // GEMM2: out-col base

    // ---- prologue: afA direct from global; stage w1 chunk 0 ----------------
    bf16x8 afA[2][8];                    // ln rows R0g1..+31 x K=256
#pragma unroll
    for (int mt = 0; mt < 2; ++mt)
#pragma unroll
        for (int kk = 0; kk < 8; ++kk) {
            const int row = bm + R0g1 + mt * 16 + l16;
            afA[mt][kk] = *(const bf16x8*)&ln[(size_t)row * 256 + (kk * 4 + quad) * 8];
        }
#pragma unroll
    for (int i = 0; i < 4; ++i) {
        const int r0 = (wave * 4 + i) * 2;
        const int r  = r0 + (lane >> 5);
        gl_lds16(w1T + (size_t)r * 256 + (((lane & 31) ^ (r & 7)) << 3),
                 w1s0 + r0 * 256);
    }
    __syncthreads();

    f32x4 acc2[4][4] = {};               // out[m=M0+mt*16+l16][n=N0+nt*16+q*4+r]

#pragma unroll 1
    for (int c = 0; c < 16; ++c) {
        ushort* const w1cur = (c & 1) ? w1s1 : w1s0;
        ushort* const w1nxt = (c & 1) ? w1s0 : w1s1;
        ushort* const hcur  = (c & 1) ? hs1  : hs0;
        ushort* const hprv  = (c & 1) ? hs0  : hs1;

        // -- issue stage w1(c+1) (drained at the barrier below) --
        if (c < 15) {
#pragma unroll
            for (int i = 0; i < 4; ++i) {
                const int r0 = (wave * 4 + i) * 2;
                const int r  = r0 + (lane >> 5);
                gl_lds16(w1T + (size_t)((c + 1) * 64 + r) * 256
                             + (((lane & 31) ^ (r & 7)) << 3),
                         w1nxt + r0 * 256);
            }
        }

        // -- load w2 frags for chunk c-1 (global, coalesced, latency hidden
        //    under GEMM1) --
        bf16x8 w2f[2][4];
        if (c >= 1) {
#pragma unroll
            for (int kk = 0; kk < 2; ++kk) {
                const int g = kk * 4 + quad;
                const ushort* base = w2R + ((size_t)((c - 1) * 8 + g)) * 2048;
#pragma unroll
                for (int nt = 0; nt < 4; ++nt) {
                    const int n = N0 + nt * 16 + l16;
                    w2f[kk][nt] = *(const bf16x8*)(base + n * 8);
                }
            }
        }

        // -- GEMM1(c): H = ln @ w1[c]  (A regs, B LDS) --
        f32x4 acc1[2][2] = {};
#pragma unroll
        for (int kk = 0; kk < 8; ++kk) {
            bf16x8 wf[2];
#pragma unroll
            for (int nt = 0; nt < 2; ++nt) {
                const int n = C0g1 + nt * 16 + l16;
                wf[nt] = *(const bf16x8*)
                    &w1cur[n * 256 + (((kk * 4 + quad) ^ (n & 7)) << 3)];
            }
#pragma unroll
            for (int mt = 0; mt < 2; ++mt)
#pragma unroll
                for (int nt = 0; nt < 2; ++nt)
                    acc1[mt][nt] = __builtin_amdgcn_mfma_f32_16x16x32_bf16(
                        wf[nt], afA[mt][kk], acc1[mt][nt], 0, 0, 0);
        }

        // -- H(c) -> hcur: relu(acc1 + b1), packed b64, swizzled --
        {
            float4 bb[2];
#pragma unroll
            for (int nt = 0; nt < 2; ++nt)
                bb[nt] = *(const float4*)&b1v[c * 64 + C0g1 + nt * 16 + quad * 4];
#pragma unroll
            for (int mt = 0; mt < 2; ++mt) {
                const int m = R0g1 + mt * 16 + l16;
#pragma unroll
                for (int nt = 0; nt < 2; ++nt) {
                    const int oct = (C0g1 >> 2) + nt * 4 + quad;
                    ushort4 pk;
                    pk.x = f2b(fmaxf(acc1[mt][nt][0] + bb[nt].x, 0.f));
                    pk.y = f2b(fmaxf(acc1[mt][nt][1] + bb[nt].y, 0.f));
                    pk.z = f2b(fmaxf(acc1[mt][nt][2] + bb[nt].z, 0.f));
                    pk.w = f2b(fmaxf(acc1[mt][nt][3] + bb[nt].w, 0.f));
                    *(ushort4*)&hcur[m * 64 + ((oct ^ ((m & 7) << 1)) << 2)] = pk;
                }
            }
        }

        // -- GEMM2(c-1): acc2 += H(c-1) @ w2[c-1]  (H LDS, w2 regs) --
        if (c >= 1) {
#pragma unroll
            for (int kk = 0; kk < 2; ++kk) {
                const int g = kk * 4 + quad;
                bf16x8 hf[4];
#pragma unroll
                for (int mt = 0; mt < 4; ++mt) {
                    const int m = M0 + mt * 16 + l16;
                    hf[mt] = *(const bf16x8*)&hprv[m * 64 + ((g ^ (m & 7)) << 3)];
                }
#pragma unroll
                for (int mt = 0; mt < 4; ++mt)
#pragma unroll
                    for (int nt = 0; nt < 4; ++nt)
                        acc2[mt][nt] = __builtin_amdgcn_mfma_f32_16x16x32_bf16(
                            w2f[kk][nt], hf[mt], acc2[mt][nt], 0, 0, 0);
            }
        }
        __syncthreads();   // drain w1 stage; publish h(c); all reads done
    }

    // ---- epilogue: GEMM2(15) from hs1, then out = x + acc2 + b2 -----------
    {
        bf16x8 w2f[2][4];
#pragma unroll
        for (int kk = 0; kk < 2; ++kk) {
            const int g = kk * 4 + quad;
            const ushort* base = w2R + ((size_t)(15 * 8 + g)) * 2048;
#pragma unroll
            for (int nt = 0; nt < 4; ++nt) {
                const int n = N0 + nt * 16 + l16;
                w2f[kk][nt] = *(const bf16x8*)(base + n * 8);
            }
        }
#pragma unroll
        for (int kk = 0; kk < 2; ++kk) {
            const int g = kk * 4 + quad;
            bf16x8 hf[4];
#pragma unroll
            for (int mt = 0; mt < 4; ++mt) {
                const int m = M0 + mt * 16 + l16;
                hf[mt] = *(const bf16x8*)&hs1[m * 64 + ((g ^ (m & 7)) << 3)];
            }
#pragma unroll
            for (int mt = 0; mt < 4; ++mt)
#pragma unroll
                for (int nt = 0; nt < 4; ++nt)
                    acc2[mt][nt] = __builtin_amdgcn_mfma_f32_16x16x32_bf16(
                        w2f[kk][nt], hf[mt], acc2[mt][nt], 0, 0, 0);
        }
    }

#pragma unroll
    for (int mt = 0; mt < 4; ++mt) {
        const int row = bm + M0 + mt * 16 + l16;
#pragma unroll
        for (int nt = 0; nt < 4; ++nt) {
            const int col = N0 + nt * 16 + quad * 4;
            float4* p = (float4*)(out + (size_t)row * 256 + col);
            const float4 b4 = *(const float4*)&b2v[col];
            float4 v = *p;
            v.x = v.x + acc2[mt][nt][0] + b4.x;
            v.y = v.y + acc2[mt][nt][1] + b4.y;
            v.z = v.z + acc2[mt][nt][2] + b4.z;
            v.w = v.w + acc2[mt][nt][3] + b4.w;
            *p = v;
        }
    }
}

// ---------------------------------------------------------------------------
// Fused softmax + deformable bilinear sampling (unchanged).
// ---------------------------------------------------------------------------
__device__ __forceinline__ void acc8(float* a, uint4 g, float w) {
    a[0] = fmaf(w, __uint_as_float(g.x << 16), a[0]);
    a[1] = fmaf(w, __uint_as_float(g.x), a[1]);
    a[2] = fmaf(w, __uint_as_float(g.y << 16), a[2]);
    a[3] = fmaf(w, __uint_as_float(g.y), a[3]);
    a[4] = fmaf(w, __uint_as_float(g.z << 16), a[4]);
    a[5] = fmaf(w, __uint_as_float(g.z), a[5]);
    a[6] = fmaf(w, __uint_as_float(g.w << 16), a[6]);
    a[7] = fmaf(w, __uint_as_float(g.w), a[7]);
}

__global__ __launch_bounds__(256)
void sample_k(const ushort* __restrict__ value, const ushort* __restrict__ projc,
              ushort* __restrict__ acc)
{
    __shared__ float sOff[8][192];
    __shared__ float sAttn[8][96];

    const int tid = threadIdx.x;
    const int bid = blockIdx.x;                       // 0..4095
    const int bq0 = (((bid & 7) << 9) | (bid >> 3)) << 3;   // XCD stripe swizzle

    for (int i = tid; i < 8 * 288; i += 256) {
        const int qw = i / 288, j = i - qw * 288;
        const float v = __uint_as_float((uint32_t)projc[(size_t)(bq0 + qw) * 384 + j] << 16);
        if (j < 192) sOff[qw][j] = v;
        else         sAttn[qw][j - 192] = v;
    }
    __syncthreads();

    if (tid < 64) {
        const int qw = tid >> 3, h = tid & 7;
        float* row = &sAttn[qw][h * 12];
        float m = row[0];
#pragma unroll
        for (int j = 1; j < 12; ++j) m = fmaxf(m, row[j]);
        float s = 0.f;
#pragma unroll
        for (int j = 0; j < 12; ++j) { const float e = __expf(row[j] - m); row[j] = e; s += e; }
        const float inv = 1.f / s;
#pragma unroll
        for (int j = 0; j < 12; ++j) row[j] *= inv;
    }
    __syncthreads();

    const int wave = tid >> 6, lane = tid & 63;
    const int qh = lane >> 5;
    const int h  = (lane >> 2) & 7;
    const int cg = lane & 3;
    const int qw = wave * 2 + qh;
    const int bq = bq0 + qw;
    const int n  = bq >> 14;
    const int q  = bq & 16383;

    const float qx = (float)(q & 127) + 0.5f;
    const float qy = (float)(q >> 7) + 0.5f;

    const int LSIc[3] = {0, 16384, 20480};

    float a[8] = {0.f, 0.f, 0.f, 0.f, 0.f, 0.f, 0.f, 0.f};
    const ushort* vbase = value + (size_t)n * LENIN * D_MODEL + h * D_HEAD + cg * 8;

#pragma unroll
    for (int l = 0; l < N_LEVELS; ++l) {
        const int   W     = 128 >> l;
        const int   SH    = 7 - l;
        const float scale = 1.f / (float)(1 << l);
        const float cx    = qx * scale - 0.5f;
        const float cy    = qy * scale - 0.5f;
        const ushort* vlev = vbase + ((size_t)LSIc[l] << 8);
#pragma unroll
        for (int p = 0; p < N_POINTS; ++p) {
            const int ob = (h * N_LEVELS + l) * (N_POINTS * 2) + p * 2;
            const float aw = sAttn[qw][h * 12 + l * 4 + p];
            const float x = cx + sOff[qw][ob];
            const float y = cy + sOff[qw][ob + 1];
            const float x0f = floorf(x), y0f = floorf(y);
            const int x0 = (int)x0f, y0 = (int)y0f;
            const float dx = x - x0f, dy = y - y0f;
            float wx1 = dx * aw, wx0 = aw - wx1;
            float wy1 = dy,      wy0 = 1.f - dy;
            if ((unsigned)x0       > (unsigned)(W - 1)) wx0 = 0.f;
            if ((unsigned)(x0 + 1) > (unsigned)(W - 1)) wx1 = 0.f;
            if ((unsigned)y0       > (unsigned)(W - 1)) wy0 = 0.f;
            if ((unsigned)(y0 + 1) > (unsigned)(W - 1)) wy1 = 0.f;
            const int xi0 = min(max(x0, 0), W - 1);
            const int xi1 = min(max(x0 + 1, 0), W - 1);
            const int yi0 = min(max(y0, 0), W - 1);
            const int yi1 = min(max(y0 + 1, 0), W - 1);
            const uint4 g00 = *(const uint4*)(vlev + ((size_t)((yi0 << SH) + xi0) << 8));
            const uint4 g01 = *(const uint4*)(vlev + ((size_t)((yi0 << SH) + xi1) << 8));
            const uint4 g10 = *(const uint4*)(vlev + ((size_t)((yi1 << SH) + xi0) << 8));
            const uint4 g11 = *(const uint4*)(vlev + ((size_t)((yi1 << SH) + xi1) << 8));
            acc8(a, g00, wx0 * wy0);
            acc8(a, g01, wx1 * wy0);
            acc8(a, g10, wx0 * wy1);
            acc8(a, g11, wx1 * wy1);
        }
    }

    const uint32_t o0 = (uint32_t)f2b(a[0]) | ((uint32_t)f2b(a[1]) << 16);
    const uint32_t o1 = (uint32_t)f2b(a[2]) | ((uint32_t)f2b(a[3]) << 16);
    const uint32_t o2 = (uint32_t)f2b(a[4]) | ((uint32_t)f2b(a[5]) << 16);
    const uint32_t o3 = (uint32_t)f2b(a[6]) | ((uint32_t)f2b(a[7]) << 16);
    const uint4 ov = {o0, o1, o2, o3};
    *(uint4*)(acc + (size_t)bq * D_MODEL + h * D_HEAD + cg * 8) = ov;
}

// ---------------------------------------------------------------------------
// All weight prep in one launch.  w2 stored FRAG-CONTIGUOUS:
//   w2R[(k>>3)*2048 + n*8 + (k&7)] = w2[k][n]
// so a wave's GEMM2 b128 frag loads (16 lanes x consecutive n) are fully
// coalesced 256B runs from global.
// ---------------------------------------------------------------------------
__global__ __launch_bounds__(256)
void prep_all_k(const float* __restrict__ w_value, const float* __restrict__ w_out,
                const float* __restrict__ w1, const float* __restrict__ w2,
                const float* __restrict__ w_off, const float* __restrict__ b_off,
                const float* __restrict__ w_attn, const float* __restrict__ b_attn,
                ushort* __restrict__ wvT, ushort* __restrict__ woT,
                ushort* __restrict__ w1T, ushort* __restrict__ w2R,
                ushort* __restrict__ wcT, float* __restrict__ biasc)
{
    int i = blockIdx.x * 256 + threadIdx.x;
    if (i < 65536) {                                  // w_value [256][256] -> [n][k]
        const int k = i >> 8, n = i & 255;
        wvT[(size_t)n * 256 + k] = f2b(w_value[i]);
        return;
    }
    i -= 65536;
    if (i < 65536) {                                  // w_out [256][256]
        const int k = i >> 8, n = i & 255;
        woT[(size_t)n * 256 + k] = f2b(w_out[i]);
        return;
    }
    i -= 65536;
    if (i < 262144) {                                 // w1 [256][1024] -> [1024][256]
        const int k = i >> 10, n = i & 1023;
        w1T[(size_t)n * 256 + k] = f2b(w1[i]);
        return;
    }
    i -= 262144;
    if (i < 262144) {                                 // w2 [1024][256] -> frag-contig
        const int k = i >> 8, n = i & 255;
        w2R[(size_t)(k >> 3) * 2048 + n * 8 + (k & 7)] = f2b(w2[i]);
        return;
    }
    i -= 262144;
    if (i < 49152) {                                  // [w_off|w_attn|0] -> [384][128]
        const int nn = i >> 7, k = i & 127;
        float v = 0.f;
        if (nn < 192)      v = w_off[(size_t)k * 192 + nn];
        else if (nn < 288) v = w_attn[(size_t)k * 96 + (nn - 192)];
        wcT[i] = f2b(v);
        return;
    }
    i -= 49152;
    if (i < 384) {
        float b = 0.f;
        if (i < 192)      b = b_off[i];
        else if (i < 288) b = b_attn[i - 192];
        biasc[i] = b;
    }
}

// ---------------------------------------------------------------------------
extern "C" void kernel_launch(void* const* d_in, const int* in_sizes, int n_in,
                              void* d_out, int out_size, void* d_ws, size_t ws_size,
                              hipStream_t stream)
{
    const float* src     = (const float*)d_in[0];
    const float* flow    = (const float*)d_in[1];
    const float* w_value = (const float*)d_in[4];
    const float* b_value = (const float*)d_in[5];
    const float* w_off   = (const float*)d_in[6];
    const float* b_off   = (const float*)d_in[7];
    const float* w_attn  = (const float*)d_in[8];
    const float* b_attn  = (const float*)d_in[9];
    const float* w_out   = (const float*)d_in[10];
    const float* b_out   = (const float*)d_in[11];
    const float* gamma   = (const float*)d_in[12];
    const float* beta    = (const float*)d_in[13];
    const float* w1      = (const float*)d_in[14];
    const float* b1      = (const float*)d_in[15];
    const float* w2      = (const float*)d_in[16];
    const float* b2      = (const float*)d_in[17];
    float* out = (float*)d_out;
    char*  wsb = (char*)d_ws;

    // Workspace (bytes), lifetime-aliased:
    //   [0, 22MB)               value_bf
    //   [22MB, 39MB)            acc_bf
    //   [67108864, 92274688)    projc_bf (dead after sampler) -> ln_bf
    //   [92274688, ...)         bf16 weights + proj bias
    ushort* value_bf = (ushort*)(wsb);
    ushort* acc_bf   = (ushort*)(wsb + 22020096);
    ushort* projc_bf = (ushort*)(wsb + 67108864);
    ushort* ln_bf    = (ushort*)(wsb + 67108864);
    ushort* wvT      = (ushort*)(wsb + 92274688);
    ushort* woT      = (ushort*)(wsb + 92405760);
    ushort* w1T      = (ushort*)(wsb + 92536832);
    ushort* w2R      = (ushort*)(wsb + 93061120);
    ushort* wcT      = (ushort*)(wsb + 93585408);
    float*  biasc    = (float*) (wsb + 93683712);

    const int Mq = NB * LQ;     // 32768
    const int Mv = NB * LENIN;  // 43008

    // allow 96 KB dynamic LDS for the fused FFN (idempotent)
    static bool ffn_attr_done = false;
    if (!ffn_attr_done) {
        hipFuncSetAttribute((const void*)ffn_fused_k,
                            hipFuncAttributeMaxDynamicSharedMemorySize, 98304);
        ffn_attr_done = true;
    }

    // 0. all weight prep, one launch
    prep_all_k<<<2754, 256, 0, stream>>>(w_value, w_out, w1, w2,
                                         w_off, b_off, w_attn, b_attn,
                                         wvT, woT, w1T, w2R, wcT, biasc);

    // 1. value = src @ w_value + b_value  [43008 x 256] (fp32 A staged) bf16 out
    mfma_gemm<true, false, false, true><<<dim3(2, Mv / 128), 256, 0, stream>>>(
        src, wvT, b_value, nullptr, value_bf, 256, 256);

    // 2. proj = flow @ [w_off|w_attn|0] + bias  [32768 x 384] (fp32 A) bf16 out
    mfma_gemm<true, false, false, true><<<dim3(3, Mq / 128), 256, 0, stream>>>(
        flow, wcT, biasc, nullptr, projc_bf, 384, 128);

    // 3. deformable sampling (fused softmax)  [32768 x 256] bf16 out
    sample_k<<<Mq / 8, 256, 0, stream>>>(value_bf, projc_bf, acc_bf);

    // 4. x = acc @ w_out + b_out -> d_out fp32; ln = LN(x) -> bf16 (fused)
    gemm_ln_k<<<Mq / 64, 256, 0, stream>>>(
        acc_bf, woT, b_out, gamma, beta, out, ln_bf, 256);

    // 5+6 fused: out = x + relu(ln @ w1 + b1) @ w2 + b2  (v6: 1 barrier/chunk)
    ffn_fused_k<<<Mq / 128, 512, 98304, stream>>>(ln_bf, w1T, w2R, b1, b2, out);
}

// Round 7
// 250.358 us; speedup vs baseline: 1.0882x; 1.0776x over previous
//
#include <hip/hip_runtime.h>
#include <cstdint>
#include <cstddef>

#define D_MODEL  256
#define D_FLOW   128
#define D_FFN    1024
#define N_HEADS  8
#define N_LEVELS 3
#define N_POINTS 4
#define D_HEAD   32
#define LQ       16384
#define LENIN    21504
#define NB       2

typedef unsigned short ushort;
typedef __attribute__((ext_vector_type(8))) short bf16x8;   // 8 bf16 in 4 VGPRs
typedef __attribute__((ext_vector_type(4))) float f32x4;

__device__ __forceinline__ ushort f2b(float f) {            // fp32 -> bf16 RNE
    uint32_t u = __float_as_uint(f);
    uint32_t r = (u + 0x7fffu + ((u >> 16) & 1u)) >> 16;
    return (ushort)r;
}

// async 16B global->LDS copy; LDS dest = wave-uniform base + lane*16
__device__ __forceinline__ void gl_lds16(const void* g, void* l) {
    __builtin_amdgcn_global_load_lds(
        (const __attribute__((address_space(1))) unsigned int*)g,
        (__attribute__((address_space(3))) unsigned int*)l,
        16, 0, 0);
}

// ---------------------------------------------------------------------------
// bf16 MFMA GEMM: BM=BN=128, BK=64.  XCD-contiguous block swizzle (unchanged).
// ---------------------------------------------------------------------------
template<bool A_FP32, bool RELU, bool RESID, bool OUT_BF16>
__global__ __launch_bounds__(256)
void mfma_gemm(const void* __restrict__ Ain, const ushort* __restrict__ Bt,
               const float* __restrict__ bias, const float* __restrict__ resid,
               void* __restrict__ Cout, int N, int K)
{
    __shared__ ushort As[128 * 64];   // 16 KB
    __shared__ ushort Bs[128 * 64];   // 16 KB

    const int tid  = threadIdx.x;
    const int wave = tid >> 6;
    const int lane = tid & 63;
    const int quad = lane >> 4;
    const int l16  = lane & 15;
    const int wr   = (wave >> 1) * 64;
    const int wc   = (wave & 1) * 64;

    const int nx = gridDim.x;
    int lin = blockIdx.y * nx + blockIdx.x;
    const int total = nx * gridDim.y;
    if ((total & 7) == 0) lin = (lin & 7) * (total >> 3) + (lin >> 3);
    const int by = lin / nx;
    const int bx = lin - by * nx;
    const int bm = by * 128;
    const int bn = bx * 128;

    const int sr  = lane >> 3;
    const int sc  = lane & 7;
    const int gch = sc ^ sr;

    f32x4 acc[4][4] = {};
    const int swz = l16 & 7;

    for (int k0 = 0; k0 < K; k0 += 64) {
        __syncthreads();
        if (A_FP32) {
            const float* Af = (const float*)Ain;
#pragma unroll
            for (int i = 0; i < 4; ++i) {
                const int row = wave * 32 + i * 8 + sr;
                const float* p = Af + (size_t)(bm + row) * K + k0 + gch * 8;
                const float4 v0 = *(const float4*)(p);
                const float4 v1 = *(const float4*)(p + 4);
                bf16x8 pk;
                pk[0] = (short)f2b(v0.x); pk[1] = (short)f2b(v0.y);
                pk[2] = (short)f2b(v0.z); pk[3] = (short)f2b(v0.w);
                pk[4] = (short)f2b(v1.x); pk[5] = (short)f2b(v1.y);
                pk[6] = (short)f2b(v1.z); pk[7] = (short)f2b(v1.w);
                *(bf16x8*)&As[(size_t)row * 64 + sc * 8] = pk;
            }
        } else {
            const ushort* Ab = (const ushort*)Ain;
#pragma unroll
            for (int i = 0; i < 4; ++i) {
                const int row = wave * 32 + i * 8;
                gl_lds16(Ab + (size_t)(bm + row + sr) * K + k0 + gch * 8,
                         As + (size_t)row * 64);
            }
        }
#pragma unroll
        for (int i = 0; i < 4; ++i) {
            const int row = wave * 32 + i * 8;
            gl_lds16(Bt + (size_t)(bn + row + sr) * K + k0 + gch * 8,
                     Bs + (size_t)row * 64);
        }
        __syncthreads();

#pragma unroll
        for (int kk = 0; kk < 2; ++kk) {
            bf16x8 af[4], bfr[4];
#pragma unroll
            for (int mi = 0; mi < 4; ++mi) {
                const int p = (kk * 4 + quad) ^ swz;
                af[mi] = *(const bf16x8*)&As[(wr + mi * 16 + l16) * 64 + p * 8];
            }
#pragma unroll
            for (int ni = 0; ni < 4; ++ni) {
                const int p = (kk * 4 + quad) ^ swz;
                bfr[ni] = *(const bf16x8*)&Bs[(wc + ni * 16 + l16) * 64 + p * 8];
            }
#pragma unroll
            for (int mi = 0; mi < 4; ++mi)
#pragma unroll
                for (int ni = 0; ni < 4; ++ni)
                    acc[mi][ni] = __builtin_amdgcn_mfma_f32_16x16x32_bf16(
                        af[mi], bfr[ni], acc[mi][ni], 0, 0, 0);
        }
    }

#pragma unroll
    for (int mi = 0; mi < 4; ++mi) {
#pragma unroll
        for (int ni = 0; ni < 4; ++ni) {
            const int col = bn + wc + ni * 16 + l16;
            const float bb = bias[col];
#pragma unroll
            for (int r = 0; r < 4; ++r) {
                const int row = bm + wr + mi * 16 + quad * 4 + r;
                const size_t idx = (size_t)row * N + col;
                float c = acc[mi][ni][r] + bb;
                if (RELU)  c = fmaxf(c, 0.f);
                if (RESID) c += resid[idx];
                if (OUT_BF16) ((ushort*)Cout)[idx] = f2b(c);
                else          ((float*)Cout)[idx]  = c;
            }
        }
    }
}

// ---------------------------------------------------------------------------
// Fused out-proj GEMM + LayerNorm + FFN (v7 mega-fusion):
//   out = x + relu(LN(x) @ w1 + b1) @ w2 + b2,  x = acc @ w_out + b_out
// x and ln never leave the CU (removes the 100 MB x/ln HBM round-trip and a
// kernel launch).  Grid 256, 512 thr (8 waves), BM=128.
// Phase 1: x-GEMM (BK=64, 4 steps, mfma_gemm staging pattern; operand-swapped
//   so x lands in acc2's layout; K ascending 8x32 slices = bit-identical to
//   the old gemm_ln x).  acc2 is SEEDED with x (MFMA C-in) -> epilogue is a
//   pure write (no RMW).
// Phase 2: LN partials -> mu/rsqrt in LDS (same formula), ln bf16 -> lnS
//   (v6 XOR layout).
// Phase 3: v6 FFN loop verbatim; afA reads lnS instead of global.
// LDS (97 KB dynamic), phase-aliased; all transitions barrier-separated:
//   P1: aS[0,16K) wS[16K,48K) | LN: sP[0,8.5K) sQ[8.5,17K) lnS[32K,96K)
//   mu/ri[96K,97K) | P3: w1s0[0,32K) w1s1[32K,64K) hs0[64K,80K) hs1[80,96K).
// fp-order deltas vs 2-kernel path: LN partial order (~1e-7 mu), residual
// seeded-first (~1e-6) -- both << absmax 0.0049.
// ---------------------------------------------------------------------------
__global__ __launch_bounds__(512, 2)
void ffn_fused_k(const ushort* __restrict__ accb, const ushort* __restrict__ woT,
                 const ushort* __restrict__ w1T,  const ushort* __restrict__ w2R,
                 const float* __restrict__ b_out, const float* __restrict__ gamma,
                 const float* __restrict__ beta,  const float* __restrict__ b1v,
                 const float* __restrict__ b2v,   float* __restrict__ out)
{
    extern __shared__ ushort smem[];               // 99328 B dynamic
    // phase-1 / LN aliases
    ushort* const aS  = smem;                      // [128 m][64 k] 16 KB
    ushort* const wS  = smem + 8192;               // [256 n][64 k] 32 KB
    float*  const sP  = (float*)smem;              // [128][17] partial sums
    float*  const sQ  = (float*)(smem + 4352);     // [128][17] partial sumsq
    ushort* const lnS = smem + 16384;              // [128][256] 64 KB @32K..96K
    float*  const sMu = (float*)(smem + 49152);    // 128 f32 @96K
    float*  const sRi = (float*)(smem + 49408);    // 128 f32 @96.5K
    // phase-3 aliases (v6 layout)
    ushort* const w1s0 = smem;                     // [64 n][256 k] 32 KB
    ushort* const w1s1 = smem + 16384;             // 32 KB
    ushort* const hs0  = smem + 32768;             // [128 m][64 n] 16 KB
    ushort* const hs1  = smem + 40960;             // 16 KB

    const int tid  = threadIdx.x;
    const int wave = tid >> 6;
    const int lane = tid & 63;
    const int quad = lane >> 4;
    const int l16  = lane & 15;
    const int bm   = blockIdx.x * 128;

    const int M0   = (wave & 1) * 64;    // x/out row base
    const int N0   = (wave >> 1) * 64;   // x/out col base
    const int R0g1 = (wave >> 1) * 32;   // GEMM1 ln-row base
    const int C0g1 = (wave & 1) * 32;    // GEMM1 w1-col base (within chunk)

    const int sr  = lane >> 3;
    const int sc  = lane & 7;
    const int gch = sc ^ sr;

    f32x4 acc2[4][4] = {};               // x, then += ffn2

    // ================= phase 1: x = acc @ w_out =================
    for (int k0 = 0; k0 < 256; k0 += 64) {
        __syncthreads();
#pragma unroll
        for (int i = 0; i < 2; ++i) {
            const int r0 = wave * 16 + i * 8;
            gl_lds16(accb + (size_t)(bm + r0 + sr) * 256 + k0 + gch * 8,
                     aS + r0 * 64);
        }
#pragma unroll
        for (int i = 0; i < 4; ++i) {
            const int r0 = wave * 32 + i * 8;
            gl_lds16(woT + (size_t)(r0 + sr) * 256 + k0 + gch * 8,
                     wS + r0 * 64);
        }
        __syncthreads();

#pragma unroll
        for (int kk = 0; kk < 2; ++kk) {
            const int g = kk * 4 + quad;
            bf16x8 af[4], wf[4];
#pragma unroll
            for (int mt = 0; mt < 4; ++mt) {
                const int m = M0 + mt * 16 + l16;
                af[mt] = *(const bf16x8*)&aS[m * 64 + ((g ^ (m & 7)) << 3)];
            }
#pragma unroll
            for (int nt = 0; nt < 4; ++nt) {
                const int n = N0 + nt * 16 + l16;
                wf[nt] = *(const bf16x8*)&wS[n * 64 + ((g ^ (n & 7)) << 3)];
            }
#pragma unroll
            for (int mt = 0; mt < 4; ++mt)
#pragma unroll
                for (int nt = 0; nt < 4; ++nt)
                    acc2[mt][nt] = __builtin_amdgcn_mfma_f32_16x16x32_bf16(
                        wf[nt], af[mt], acc2[mt][nt], 0, 0, 0);
        }
    }
    __syncthreads();                     // phase-1 LDS reads done

    // ================= phase 2: LayerNorm =================
    {
        float4 bo[4];
#pragma unroll
        for (int nt = 0; nt < 4; ++nt)
            bo[nt] = *(const float4*)&b_out[N0 + nt * 16 + quad * 4];
        const int widx = (wave >> 1) * 4 + quad;
#pragma unroll
        for (int mt = 0; mt < 4; ++mt) {
            const int m = M0 + mt * 16 + l16;
            float s = 0.f, s2 = 0.f;
#pragma unroll
            for (int nt = 0; nt < 4; ++nt) {
                acc2[mt][nt][0] += bo[nt].x;
                acc2[mt][nt][1] += bo[nt].y;
                acc2[mt][nt][2] += bo[nt].z;
                acc2[mt][nt][3] += bo[nt].w;
#pragma unroll
                for (int r = 0; r < 4; ++r) {
                    const float c = acc2[mt][nt][r];
                    s += c; s2 += c * c;
                }
            }
            sP[m * 17 + widx] = s;
            sQ[m * 17 + widx] = s2;
        }
    }
    __syncthreads();

    if (tid < 128) {
        float s = 0.f, s2 = 0.f;
#pragma unroll
        for (int j = 0; j < 16; ++j) { s += sP[tid * 17 + j]; s2 += sQ[tid * 17 + j]; }
        const float mu  = s * (1.f / 256.f);
        const float var = s2 * (1.f / 256.f) - mu * mu;
        sMu[tid] = mu;
        sRi[tid] = rsqrtf(var + 1e-5f);
    }
    __syncthreads();

    // mu/ri to regs (sMu/sRi live at 96K, untouched by later phases)
    float mu4[4], ri4[4];
#pragma unroll
    for (int mt = 0; mt < 4; ++mt) {
        const int m = M0 + mt * 16 + l16;
        mu4[mt] = sMu[m]; ri4[mt] = sRi[m];
    }

    // stage w1 chunk 0 -> w1s0 [0,32K) (sP/sQ dead)
#pragma unroll
    for (int i = 0; i < 4; ++i) {
        const int r0 = (wave * 4 + i) * 2;
        const int r  = r0 + (lane >> 5);
        gl_lds16(w1T + (size_t)r * 256 + (((lane & 31) ^ (r & 7)) << 3),
                 w1s0 + r0 * 256);
    }

    // ln -> lnS (bf16, XOR layout matching phase-3 afA reads)
#pragma unroll
    for (int mt = 0; mt < 4; ++mt) {
        const int m = M0 + mt * 16 + l16;
        const float mu = mu4[mt], ri = ri4[mt];
#pragma unroll
        for (int nt = 0; nt < 4; ++nt) {
            const int col0 = N0 + nt * 16 + quad * 4;
            const float4 g4 = *(const float4*)&gamma[col0];
            const float4 b4 = *(const float4*)&beta[col0];
            ushort4 pk;
            pk.x = f2b((acc2[mt][nt][0] - mu) * ri * g4.x + b4.x);
            pk.y = f2b((acc2[mt][nt][1] - mu) * ri * g4.y + b4.y);
            pk.z = f2b((acc2[mt][nt][2] - mu) * ri * g4.z + b4.z);
            pk.w = f2b((acc2[mt][nt][3] - mu) * ri * g4.w + b4.w);
            const int c8 = col0 >> 3;
            *(ushort4*)&lnS[m * 256 + ((c8 ^ (m & 7)) << 3) + (quad & 1) * 4] = pk;
        }
    }
    __syncthreads();                     // lnS visible; w1s0 stage drained

    bf16x8 afA[2][8];                    // ln rows R0g1..+31 x K=256
#pragma unroll
    for (int mt = 0; mt < 2; ++mt)
#pragma unroll
        for (int kk = 0; kk < 8; ++kk) {
            const int row = R0g1 + mt * 16 + l16;
            afA[mt][kk] = *(const bf16x8*)
                &lnS[row * 256 + (((kk * 4 + quad) ^ (row & 7)) << 3)];
        }
    __syncthreads();                     // lnS region released for phase 3

    // ================= phase 3: FFN loop (v6 verbatim) =================
#pragma unroll 1
    for (int c = 0; c < 16; ++c) {
        ushort* const w1cur = (c & 1) ? w1s1 : w1s0;
        ushort* const w1nxt = (c & 1) ? w1s0 : w1s1;
        ushort* const hcur  = (c & 1) ? hs1  : hs0;
        ushort* const hprv  = (c & 1) ? hs0  : hs1;

        if (c < 15) {
#pragma unroll
            for (int i = 0; i < 4; ++i) {
                const int r0 = (wave * 4 + i) * 2;
                const int r  = r0 + (lane >> 5);
                gl_lds16(w1T + (size_t)((c + 1) * 64 + r) * 256
                             + (((lane & 31) ^ (r & 7)) << 3),
                         w1nxt + r0 * 256);
            }
        }

        bf16x8 w2f[2][4];
        if (c >= 1) {
#pragma unroll
            for (int kk = 0; kk < 2; ++kk) {
                const int g = kk * 4 + quad;
                const ushort* base = w2R + ((size_t)((c - 1) * 8 + g)) * 2048;
#pragma unroll
                for (int nt = 0; nt < 4; ++nt) {
                    const int n = N0 + nt * 16 + l16;
                    w2f[kk][nt] = *(const bf16x8*)(base + n * 8);
                }
            }
        }

        f32x4 acc1[2][2] = {};
#pragma unroll
        for (int kk = 0; kk < 8; ++kk) {
            bf16x8 wf[2];
#pragma unroll
            for (int nt = 0; nt < 2; ++nt) {
                const int n = C0g1 + nt * 16 + l16;
                wf[nt] = *(const bf16x8*)
                    &w1cur[n * 256 + (((kk * 4 + quad) ^ (n & 7)) << 3)];
            }
#pragma unroll
            for (int mt = 0; mt < 2; ++mt)
#pragma unroll
                for (int nt = 0; nt < 2; ++nt)
                    acc1[mt][nt] = __builtin_amdgcn_mfma_f32_16x16x32_bf16(
                        wf[nt], afA[mt][kk], acc1[mt][nt], 0, 0, 0);
        }

        {
            float4 bb[2];
#pragma unroll
            for (int nt = 0; nt < 2; ++nt)
                bb[nt] = *(const float4*)&b1v[c * 64 + C0g1 + nt * 16 + quad * 4];
#pragma unroll
            for (int mt = 0; mt < 2; ++mt) {
                const int m = R0g1 + mt * 16 + l16;
#pragma unroll
                for (int nt = 0; nt < 2; ++nt) {
                    const int oct = (C0g1 >> 2) + nt * 4 + quad;
                    ushort4 pk;
                    pk.x = f2b(fmaxf(acc1[mt][nt][0] + bb[nt].x, 0.f));
                    pk.y = f2b(fmaxf(acc1[mt][nt][1] + bb[nt].y, 0.f));
                    pk.z = f2b(fmaxf(acc1[mt][nt][2] + bb[nt].z, 0.f));
                    pk.w = f2b(fmaxf(acc1[mt][nt][3] + bb[nt].w, 0.f));
                    *(ushort4*)&hcur[m * 64 + ((oct ^ ((m & 7) << 1)) << 2)] = pk;
                }
            }
        }

        if (c >= 1) {
#pragma unroll
            for (int kk = 0; kk < 2; ++kk) {
                const int g = kk * 4 + quad;
                bf16x8 hf[4];
#pragma unroll
                for (int mt = 0; mt < 4; ++mt) {
                    const int m = M0 + mt * 16 + l16;
                    hf[mt] = *(const bf16x8*)&hprv[m * 64 + ((g ^ (m & 7)) << 3)];
                }
#pragma unroll
                for (int mt = 0; mt < 4; ++mt)
#pragma unroll
                    for (int nt = 0; nt < 4; ++nt)
                        acc2[mt][nt] = __builtin_amdgcn_mfma_f32_16x16x32_bf16(
                            w2f[kk][nt], hf[mt], acc2[mt][nt], 0, 0, 0);
            }
        }
        __syncthreads();
    }

    // epilogue: GEMM2(15) from hs1
    {
        bf16x8 w2f[2][4];
#pragma unroll
        for (int kk = 0; kk < 2; ++kk) {
            const int g = kk * 4 + quad;
            const ushort* base = w2R + ((size_t)(15 * 8 + g)) * 2048;
#pragma unroll
            for (int nt = 0; nt < 4; ++nt) {
                const int n = N0 + nt * 16 + l16;
                w2f[kk][nt] = *(const bf16x8*)(base + n * 8);
            }
        }
#pragma unroll
        for (int kk = 0; kk < 2; ++kk) {
            const int g = kk * 4 + quad;
            bf16x8 hf[4];
#pragma unroll
            for (int mt = 0; mt < 4; ++mt) {
                const int m = M0 + mt * 16 + l16;
                hf[mt] = *(const bf16x8*)&hs1[m * 64 + ((g ^ (m & 7)) << 3)];
            }
#pragma unroll
            for (int mt = 0; mt < 4; ++mt)
#pragma unroll
                for (int nt = 0; nt < 4; ++nt)
                    acc2[mt][nt] = __builtin_amdgcn_mfma_f32_16x16x32_bf16(
                        w2f[kk][nt], hf[mt], acc2[mt][nt], 0, 0, 0);
        }
    }

    // out = acc2 (= x + ffn2) + b2 : pure write, no RMW
#pragma unroll
    for (int mt = 0; mt < 4; ++mt) {
        const int row = bm + M0 + mt * 16 + l16;
#pragma unroll
        for (int nt = 0; nt < 4; ++nt) {
            const int col = N0 + nt * 16 + quad * 4;
            const float4 b4 = *(const float4*)&b2v[col];
            float4 v;
            v.x = acc2[mt][nt][0] + b4.x;
            v.y = acc2[mt][nt][1] + b4.y;
            v.z = acc2[mt][nt][2] + b4.z;
            v.w = acc2[mt][nt][3] + b4.w;
            *(float4*)(out + (size_t)row * 256 + col) = v;
        }
    }
}

// ---------------------------------------------------------------------------
// Fused softmax + deformable bilinear sampling (unchanged).
// ---------------------------------------------------------------------------
__device__ __forceinline__ void acc8(float* a, uint4 g, float w) {
    a[0] = fmaf(w, __uint_as_float(g.x << 16), a[0]);
    a[1] = fmaf(w, __uint_as_float(g.x), a[1]);
    a[2] = fmaf(w, __uint_as_float(g.y << 16), a[2]);
    a[3] = fmaf(w, __uint_as_float(g.y), a[3]);
    a[4] = fmaf(w, __uint_as_float(g.z << 16), a[4]);
    a[5] = fmaf(w, __uint_as_float(g.z), a[5]);
    a[6] = fmaf(w, __uint_as_float(g.w << 16), a[6]);
    a[7] = fmaf(w, __uint_as_float(g.w), a[7]);
}

__global__ __launch_bounds__(256)
void sample_k(const ushort* __restrict__ value, const ushort* __restrict__ projc,
              ushort* __restrict__ acc)
{
    __shared__ float sOff[8][192];
    __shared__ float sAttn[8][96];

    const int tid = threadIdx.x;
    const int bid = blockIdx.x;                       // 0..4095
    const int bq0 = (((bid & 7) << 9) | (bid >> 3)) << 3;   // XCD stripe swizzle

    for (int i = tid; i < 8 * 288; i += 256) {
        const int qw = i / 288, j = i - qw * 288;
        const float v = __uint_as_float((uint32_t)projc[(size_t)(bq0 + qw) * 384 + j] << 16);
        if (j < 192) sOff[qw][j] = v;
        else         sAttn[qw][j - 192] = v;
    }
    __syncthreads();

    if (tid < 64) {
        const int qw = tid >> 3, h = tid & 7;
        float* row = &sAttn[qw][h * 12];
        float m = row[0];
#pragma unroll
        for (int j = 1; j < 12; ++j) m = fmaxf(m, row[j]);
        float s = 0.f;
#pragma unroll
        for (int j = 0; j < 12; ++j) { const float e = __expf(row[j] - m); row[j] = e; s += e; }
        const float inv = 1.f / s;
#pragma unroll
        for (int j = 0; j < 12; ++j) row[j] *= inv;
    }
    __syncthreads();

    const int wave = tid >> 6, lane = tid & 63;
    const int qh = lane >> 5;
    const int h  = (lane >> 2) & 7;
    const int cg = lane & 3;
    const int qw = wave * 2 + qh;
    const int bq = bq0 + qw;
    const int n  = bq >> 14;
    const int q  = bq & 16383;

    const float qx = (float)(q & 127) + 0.5f;
    const float qy = (float)(q >> 7) + 0.5f;

    const int LSIc[3] = {0, 16384, 20480};

    float a[8] = {0.f, 0.f, 0.f, 0.f, 0.f, 0.f, 0.f, 0.f};
    const ushort* vbase = value + (size_t)n * LENIN * D_MODEL + h * D_HEAD + cg * 8;

#pragma unroll
    for (int l = 0; l < N_LEVELS; ++l) {
        const int   W     = 128 >> l;
        const int   SH    = 7 - l;
        const float scale = 1.f / (float)(1 << l);
        const float cx    = qx * scale - 0.5f;
        const float cy    = qy * scale - 0.5f;
        const ushort* vlev = vbase + ((size_t)LSIc[l] << 8);
#pragma unroll
        for (int p = 0; p < N_POINTS; ++p) {
            const int ob = (h * N_LEVELS + l) * (N_POINTS * 2) + p * 2;
            const float aw = sAttn[qw][h * 12 + l * 4 + p];
            const float x = cx + sOff[qw][ob];
            const float y = cy + sOff[qw][ob + 1];
            const float x0f = floorf(x), y0f = floorf(y);
            const int x0 = (int)x0f, y0 = (int)y0f;
            const float dx = x - x0f, dy = y - y0f;
            float wx1 = dx * aw, wx0 = aw - wx1;
            float wy1 = dy,      wy0 = 1.f - dy;
            if ((unsigned)x0       > (unsigned)(W - 1)) wx0 = 0.f;
            if ((unsigned)(x0 + 1) > (unsigned)(W - 1)) wx1 = 0.f;
            if ((unsigned)y0       > (unsigned)(W - 1)) wy0 = 0.f;
            if ((unsigned)(y0 + 1) > (unsigned)(W - 1)) wy1 = 0.f;
            const int xi0 = min(max(x0, 0), W - 1);
            const int xi1 = min(max(x0 + 1, 0), W - 1);
            const int yi0 = min(max(y0, 0), W - 1);
            const int yi1 = min(max(y0 + 1, 0), W - 1);
            const uint4 g00 = *(const uint4*)(vlev + ((size_t)((yi0 << SH) + xi0) << 8));
            const uint4 g01 = *(const uint4*)(vlev + ((size_t)((yi0 << SH) + xi1) << 8));
            const uint4 g10 = *(const uint4*)(vlev + ((size_t)((yi1 << SH) + xi0) << 8));
            const uint4 g11 = *(const uint4*)(vlev + ((size_t)((yi1 << SH) + xi1) << 8));
            acc8(a, g00, wx0 * wy0);
            acc8(a, g01, wx1 * wy0);
            acc8(a, g10, wx0 * wy1);
            acc8(a, g11, wx1 * wy1);
        }
    }

    const uint32_t o0 = (uint32_t)f2b(a[0]) | ((uint32_t)f2b(a[1]) << 16);
    const uint32_t o1 = (uint32_t)f2b(a[2]) | ((uint32_t)f2b(a[3]) << 16);
    const uint32_t o2 = (uint32_t)f2b(a[4]) | ((uint32_t)f2b(a[5]) << 16);
    const uint32_t o3 = (uint32_t)f2b(a[6]) | ((uint32_t)f2b(a[7]) << 16);
    const uint4 ov = {o0, o1, o2, o3};
    *(uint4*)(acc + (size_t)bq * D_MODEL + h * D_HEAD + cg * 8) = ov;
}

// ---------------------------------------------------------------------------
// All weight prep in one launch.  w2 stored FRAG-CONTIGUOUS:
//   w2R[(k>>3)*2048 + n*8 + (k&7)] = w2[k][n]
// ---------------------------------------------------------------------------
__global__ __launch_bounds__(256)
void prep_all_k(const float* __restrict__ w_value, const float* __restrict__ w_out,
                const float* __restrict__ w1, const float* __restrict__ w2,
                const float* __restrict__ w_off, const float* __restrict__ b_off,
                const float* __restrict__ w_attn, const float* __restrict__ b_attn,
                ushort* __restrict__ wvT, ushort* __restrict__ woT,
                ushort* __restrict__ w1T, ushort* __restrict__ w2R,
                ushort* __restrict__ wcT, float* __restrict__ biasc)
{
    int i = blockIdx.x * 256 + threadIdx.x;
    if (i < 65536) {                                  // w_value [256][256] -> [n][k]
        const int k = i >> 8, n = i & 255;
        wvT[(size_t)n * 256 + k] = f2b(w_value[i]);
        return;
    }
    i -= 65536;
    if (i < 65536) {                                  // w_out [256][256]
        const int k = i >> 8, n = i & 255;
        woT[(size_t)n * 256 + k] = f2b(w_out[i]);
        return;
    }
    i -= 65536;
    if (i < 262144) {                                 // w1 [256][1024] -> [1024][256]
        const int k = i >> 10, n = i & 1023;
        w1T[(size_t)n * 256 + k] = f2b(w1[i]);
        return;
    }
    i -= 262144;
    if (i < 262144) {                                 // w2 [1024][256] -> frag-contig
        const int k = i >> 8, n = i & 255;
        w2R[(size_t)(k >> 3) * 2048 + n * 8 + (k & 7)] = f2b(w2[i]);
        return;
    }
    i -= 262144;
    if (i < 49152) {                                  // [w_off|w_attn|0] -> [384][128]
        const int nn = i >> 7, k = i & 127;
        float v = 0.f;
        if (nn < 192)      v = w_off[(size_t)k * 192 + nn];
        else if (nn < 288) v = w_attn[(size_t)k * 96 + (nn - 192)];
        wcT[i] = f2b(v);
        return;
    }
    i -= 49152;
    if (i < 384) {
        float b = 0.f;
        if (i < 192)      b = b_off[i];
        else if (i < 288) b = b_attn[i - 192];
        biasc[i] = b;
    }
}

// ---------------------------------------------------------------------------
extern "C" void kernel_launch(void* const* d_in, const int* in_sizes, int n_in,
                              void* d_out, int out_size, void* d_ws, size_t ws_size,
                              hipStream_t stream)
{
    const float* src     = (const float*)d_in[0];
    const float* flow    = (const float*)d_in[1];
    const float* w_value = (const float*)d_in[4];
    const float* b_value = (const float*)d_in[5];
    const float* w_off   = (const float*)d_in[6];
    const float* b_off   = (const float*)d_in[7];
    const float* w_attn  = (const float*)d_in[8];
    const float* b_attn  = (const float*)d_in[9];
    const float* w_out   = (const float*)d_in[10];
    const float* b_out   = (const float*)d_in[11];
    const float* gamma   = (const float*)d_in[12];
    const float* beta    = (const float*)d_in[13];
    const float* w1      = (const float*)d_in[14];
    const float* b1      = (const float*)d_in[15];
    const float* w2      = (const float*)d_in[16];
    const float* b2      = (const float*)d_in[17];
    float* out = (float*)d_out;
    char*  wsb = (char*)d_ws;

    // Workspace (bytes), lifetime-aliased:
    //   [0, 22MB)               value_bf
    //   [22MB, 39MB)            acc_bf
    //   [67108864, 92274688)    projc_bf
    //   [92274688, ...)         bf16 weights + proj bias
    ushort* value_bf = (ushort*)(wsb);
    ushort* acc_bf   = (ushort*)(wsb + 22020096);
    ushort* projc_bf = (ushort*)(wsb + 67108864);
    ushort* wvT      = (ushort*)(wsb + 92274688);
    ushort* woT      = (ushort*)(wsb + 92405760);
    ushort* w1T      = (ushort*)(wsb + 92536832);
    ushort* w2R      = (ushort*)(wsb + 93061120);
    ushort* wcT      = (ushort*)(wsb + 93585408);
    float*  biasc    = (float*) (wsb + 93683712);

    const int Mq = NB * LQ;     // 32768
    const int Mv = NB * LENIN;  // 43008

    // allow 97 KB dynamic LDS for the fused kernel (idempotent)
    static bool ffn_attr_done = false;
    if (!ffn_attr_done) {
        hipFuncSetAttribute((const void*)ffn_fused_k,
                            hipFuncAttributeMaxDynamicSharedMemorySize, 99328);
        ffn_attr_done = true;
    }

    // 0. all weight prep, one launch
    prep_all_k<<<2754, 256, 0, stream>>>(w_value, w_out, w1, w2,
                                         w_off, b_off, w_attn, b_attn,
                                         wvT, woT, w1T, w2R, wcT, biasc);

    // 1. value = src @ w_value + b_value  [43008 x 256] (fp32 A staged) bf16 out
    mfma_gemm<true, false, false, true><<<dim3(2, Mv / 128), 256, 0, stream>>>(
        src, wvT, b_value, nullptr, value_bf, 256, 256);

    // 2. proj = flow @ [w_off|w_attn|0] + bias  [32768 x 384] (fp32 A) bf16 out
    mfma_gemm<true, false, false, true><<<dim3(3, Mq / 128), 256, 0, stream>>>(
        flow, wcT, biasc, nullptr, projc_bf, 384, 128);

    // 3. deformable sampling (fused softmax)  [32768 x 256] bf16 out
    sample_k<<<Mq / 8, 256, 0, stream>>>(value_bf, projc_bf, acc_bf);

    // 4+5+6 fused: x = acc@w_out+b_out; out = x + relu(LN(x)@w1+b1)@w2 + b2
    ffn_fused_k<<<Mq / 128, 512, 99328, stream>>>(
        acc_bf, woT, w1T, w2R, b_out, gamma, beta, b1, b2, out);
}